// Round 12
// baseline (244.349 us; speedup 1.0000x reference)
//
#include <hip/hip_runtime.h>
#include <hip/hip_bf16.h>

#define BB 64
#define JJ 32
#define NN 4096
#define QD 130
#define KD 128
#define VD 130
#define HH 4
#define CT 8
#define NCH (NN / CT)                 // 512
#define TIL (NCH / 32)                // 16
#define PSTRIDE (JJ + JJ + JJ * VD)   // 4224 floats per partial block

typedef __attribute__((ext_vector_type(8))) __bf16 bf16x8;
typedef __attribute__((ext_vector_type(4))) float  f32x4;

union FW4 { unsigned int u[4]; bf16x8 v; };

#define SEL_HI 0x07060302u

__device__ __forceinline__ unsigned int packhi(float f0, float f1) {
    return __builtin_amdgcn_perm(__float_as_uint(f1), __float_as_uint(f0), SEL_HI);
}
__device__ __forceinline__ float truncbf(float f) {
    return __uint_as_float(__float_as_uint(f) & 0xFFFF0000u);
}
// truncation split: 8 floats -> hi/lo bf16x8 planes (f = h + l + O(2^-17))
__device__ __forceinline__ void split8(float4 a, float4 b, bf16x8* h, bf16x8* l) {
    FW4 H, L;
    H.u[0] = packhi(a.x, a.y);
    H.u[1] = packhi(a.z, a.w);
    H.u[2] = packhi(b.x, b.y);
    H.u[3] = packhi(b.z, b.w);
    L.u[0] = packhi(a.x - truncbf(a.x), a.y - truncbf(a.y));
    L.u[1] = packhi(a.z - truncbf(a.z), a.w - truncbf(a.w));
    L.u[2] = packhi(b.x - truncbf(b.x), b.y - truncbf(b.y));
    L.u[3] = packhi(b.z - truncbf(b.z), b.w - truncbf(b.w));
    *h = H.v; *l = L.v;
}

// ---------------------------------------------------------------- encoder ---
__global__ __launch_bounds__(64) void enc_kernel(
        const float* __restrict__ jq,
        const float* __restrict__ W1, const float* __restrict__ b1,
        const float* __restrict__ W2, const float* __restrict__ b2,
        float* __restrict__ qenc) {
    int row = blockIdx.x;          // b*J + j
    int t = threadIdx.x;           // 0..63
    __shared__ float x[QD];
    __shared__ float h[64];
    for (int i = t; i < QD; i += 64) x[i] = jq[row * QD + i];
    __syncthreads();
    float a0 = 0.f, a1 = 0.f;
    for (int i = 0; i < QD - 1; i += 2) {
        a0 += x[i] * W1[i * 64 + t];
        a1 += x[i + 1] * W1[(i + 1) * 64 + t];
    }
    h[t] = fmaxf(b1[t] + a0 + a1, 0.f);
    __syncthreads();
    float a[8];
    #pragma unroll
    for (int s = 0; s < 8; ++s) a[s] = b2[t + 64 * s];
    for (int i = 0; i < 64; ++i) {
        float hv = h[i];
        #pragma unroll
        for (int s = 0; s < 8; ++s) a[s] += hv * W2[i * 512 + t + 64 * s];
    }
    #pragma unroll
    for (int s = 0; s < 8; ++s) qenc[row * 512 + t + 64 * s] = a[s];
}

// -------------------------------------------------------------- attention ---
// Block = (b, chunk, head-group of 2), 256 threads = 4 waves = 2 heads x 2
// q-halves. 16x16x32 MFMA; key-permuted K layout so the P->A-frag exchange is
// 4 shfl_xor(32). 4-wave blocks break the 8-wave granularity that pinned all
// 512-thread variants to 1 block/CU: at ~150-160 total regs (VGPR+AGPR),
// 3 waves/SIMD fit -> 3 blocks/CU (37.5% occupancy). launch_bounds(256,3)
// caps at ~170 regs, ABOVE the working set (rounds 4/9 lesson: a cap below
// the working set causes spill storms). Head-group bit is the grid's HIGH bit
// so paired blocks (same b,c) tend to land on the same XCD -> L2 dedups the
// doubled K/V fetch. Kf [65] padding restored (r11's [64] doubled conflicts).
__global__ __launch_bounds__(256, 3) void attn_kernel(
        const float* __restrict__ Kg, const float* __restrict__ Vg,
        const int* __restrict__ maskg, const float* __restrict__ qenc,
        float* __restrict__ part) {
    int blk = blockIdx.x;
    int c = blk & (CT - 1);
    int b = (blk >> 3) & (BB - 1);
    int hg = blk >> 9;             // head group: heads {2hg, 2hg+1}
    int tid = threadIdx.x;
    int wid = tid >> 6;            // 0..3
    int lane = tid & 63;
    int h = hg * 2 + (wid & 1);    // head
    int qhalf = wid >> 1;          // 0: q 0..15, 1: q 16..31
    int g = lane >> 4;             // lane group 0..3
    int q15 = lane & 15;

    __shared__ __align__(16) __bf16 Kf[2][2][2][4][65][8];   // 33,280 B (dbuf)
    __shared__ __align__(16) __bf16 Vf[2][8][64][8];         // 16,384 B (single)
    __shared__ float Vt_s[2][32];                            // V cols 128,129
    __shared__ int   msks[32];

    // stage geometry: 512 K slots, 512 V slots; thread p and p+256.
    // K slot p: skey=p>>4 (perm to kh/sm), sdhi=p&15 (d0=8*sdhi)
    // V slot q: sv=q&127 (col), skb=q>>7 (row group), dst row slV
    int p0 = tid, p1 = tid + 256;
    int skey0 = p0 >> 4, sdhi0 = p0 & 15;
    int skey1 = p1 >> 4, sdhi1 = p1 & 15;
    int sa0 = skey0 >> 3, sb0 = skey0 & 7;
    int sa1 = skey1 >> 3, sb1 = skey1 & 7;
    int skh0 = sb0 >> 2, skh1 = sb1 >> 2;
    int sm0 = skh0 ? 4 * (sa0 ^ 2) + (sb0 & 3) : 4 * sa0 + sb0;
    int sm1 = skh1 ? 4 * (sa1 ^ 2) + (sb1 & 3) : 4 * sa1 + sb1;
    int slK0 = sm0 + 16 * (sdhi0 & 3), skst0 = sdhi0 >> 2;
    int slK1 = sm1 + 16 * (sdhi1 & 3), skst1 = sdhi1 >> 2;
    int sv0 = p0 & 127, skb0 = p0 >> 7;          // skb0 0..1
    int sv1 = p1 & 127, skb1 = p1 >> 7;          // skb1 2..3
    int svc0 = sv0 >> 4, slV0 = (sv0 & 15) + 16 * skb0;
    int svc1 = sv1 >> 4, slV1 = (sv1 & 15) + 16 * skb1;

    const float* Kb = Kg + (size_t)b * NN * KD;
    const float* Vb = Vg + (size_t)b * NN * VD;
    const int*   Mb = maskg + b * NN;

    float4 kfa0, kfb0, kfa1, kfb1;
    float  vf0[8], vf1[8];
    float2 vt = {0.f, 0.f};
    int    mk = 0;

    auto sloadK = [&](int T) {
        int n0 = c * NCH + T * 32;
        const float* ks0 = Kb + (size_t)(n0 + skey0) * KD + sdhi0 * 8;
        kfa0 = *(const float4*)ks0;
        kfb0 = *(const float4*)(ks0 + 4);
        const float* ks1 = Kb + (size_t)(n0 + skey1) * KD + sdhi1 * 8;
        kfa1 = *(const float4*)ks1;
        kfb1 = *(const float4*)(ks1 + 4);
    };
    auto sloadV = [&](int T) {
        int n0 = c * NCH + T * 32;
        const float* vs0 = Vb + (size_t)(n0 + skb0 * 8) * VD + sv0;
        #pragma unroll
        for (int j = 0; j < 8; ++j) vf0[j] = vs0[(size_t)j * VD];
        const float* vs1 = Vb + (size_t)(n0 + skb1 * 8) * VD + sv1;
        #pragma unroll
        for (int j = 0; j < 8; ++j) vf1[j] = vs1[(size_t)j * VD];
        if (tid < 32) {
            vt = *(const float2*)(Vb + (size_t)(n0 + tid) * VD + 128);
            mk = Mb[n0 + tid];
        }
    };
    auto swriteK = [&](int buf) {
        bf16x8 hh, ll;
        split8(kfa0, kfb0, &hh, &ll);
        *(bf16x8*)&Kf[buf][0][skh0][skst0][slK0][0] = hh;
        *(bf16x8*)&Kf[buf][1][skh0][skst0][slK0][0] = ll;
        split8(kfa1, kfb1, &hh, &ll);
        *(bf16x8*)&Kf[buf][0][skh1][skst1][slK1][0] = hh;
        *(bf16x8*)&Kf[buf][1][skh1][skst1][slK1][0] = ll;
    };
    auto swriteV = [&]() {
        bf16x8 hh, ll;
        float4 va = {vf0[0], vf0[1], vf0[2], vf0[3]};
        float4 vb2 = {vf0[4], vf0[5], vf0[6], vf0[7]};
        split8(va, vb2, &hh, &ll);
        *(bf16x8*)&Vf[0][svc0][slV0][0] = hh;
        *(bf16x8*)&Vf[1][svc0][slV0][0] = ll;
        float4 vc3 = {vf1[0], vf1[1], vf1[2], vf1[3]};
        float4 vd = {vf1[4], vf1[5], vf1[6], vf1[7]};
        split8(vc3, vd, &hh, &ll);
        *(bf16x8*)&Vf[0][svc1][slV1][0] = hh;
        *(bf16x8*)&Vf[1][svc1][slV1][0] = ll;
        if (tid < 32) {
            Vt_s[0][tid] = vt.x;
            Vt_s[1][tid] = vt.y;
            msks[tid] = mk;
        }
    };

    sloadK(0);
    sloadV(0);

    // ---- Q B-frags (hi/lo): lane holds Q[d=kst*32+g*8+j][q=qhalf*16+q15]
    bf16x8 qh[4], ql[4];
    {
        const float* qrow = qenc + (size_t)(b * JJ + qhalf * 16 + q15) * 512
                            + h * KD + g * 8;
        #pragma unroll
        for (int kst = 0; kst < 4; ++kst) {
            float4 qa = *(const float4*)(qrow + kst * 32);
            float4 qb = *(const float4*)(qrow + kst * 32 + 4);
            split8(qa, qb, &qh[kst], &ql[kst]);
        }
    }

    swriteK(0);                    // waits K(0); publishes Kf[0]
    sloadK(1);
    __builtin_amdgcn_sched_barrier(0);

    f32x4 O[8];
    #pragma unroll
    for (int vc = 0; vc < 8; ++vc)
        #pragma unroll
        for (int r = 0; r < 4; ++r) O[vc][r] = 0.f;
    float acct0 = 0.f, acct1 = 0.f;
    float m_run = -1e30f, l_run = 0.f;

    __syncthreads();               // Kf[0] visible

    for (int t = 0; t < TIL; ++t) {
        int cur = t & 1;

        // ---- A/B: publish V(t) and K(t+1) (regs loaded last iter)
        swriteV();
        if (t + 1 < TIL) swriteK(cur ^ 1);
        __builtin_amdgcn_sched_barrier(0);

        // ---- D: S = mfma(K, Q): C[m][q], 2 instances (kh) x 12 MFMA
        f32x4 S[2];
        #pragma unroll
        for (int kh = 0; kh < 2; ++kh)
            #pragma unroll
            for (int r = 0; r < 4; ++r) S[kh][r] = 0.f;
        #pragma unroll
        for (int kst = 0; kst < 4; ++kst) {
            #pragma unroll
            for (int kh = 0; kh < 2; ++kh) {
                bf16x8 khf = *(const bf16x8*)&Kf[cur][0][kh][kst][lane][0];
                bf16x8 klf = *(const bf16x8*)&Kf[cur][1][kh][kst][lane][0];
                S[kh] = __builtin_amdgcn_mfma_f32_16x16x32_bf16(khf, qh[kst], S[kh], 0, 0, 0);
                S[kh] = __builtin_amdgcn_mfma_f32_16x16x32_bf16(khf, ql[kst], S[kh], 0, 0, 0);
                S[kh] = __builtin_amdgcn_mfma_f32_16x16x32_bf16(klf, qh[kst], S[kh], 0, 0, 0);
            }
        }

        __syncthreads();           // bar1: V(t)/mask visible; no vmem in flight

        // ---- C: prefetch next tiles (fly under softmax+PV, drained at bar2)
        if (t + 2 < TIL) sloadK(t + 2);
        if (t + 1 < TIL) sloadV(t + 1);
        __builtin_amdgcn_sched_barrier(0);

        // ---- E: mask + scale + defer-max online softmax (lane's q = q15)
        unsigned int mword = (unsigned int)__ballot(msks[lane & 31] != 0);
        const float sc = 0.08838834764831845f;
        float sp[8];
        float rm = -1e30f;
        #pragma unroll
        for (int r = 0; r < 4; ++r) {
            int key0 = 8 * g + r;
            float s0 = ((mword >> key0) & 1u) ? -1e30f : S[0][r] * sc;
            sp[r] = s0;
            rm = fmaxf(rm, s0);
            int key1 = 8 * (g ^ 2) + 4 + r;
            float s1 = ((mword >> key1) & 1u) ? -1e30f : S[1][r] * sc;
            sp[4 + r] = s1;
            rm = fmaxf(rm, s1);
        }
        rm = fmaxf(rm, __shfl_xor(rm, 16));
        rm = fmaxf(rm, __shfl_xor(rm, 32));
        if (!__all(rm <= m_run + 8.f)) {          // T13 defer-max
            float mn = fmaxf(m_run, rm);
            float rs = __expf(m_run - mn);
            m_run = mn;
            l_run *= rs; acct0 *= rs; acct1 *= rs;
            #pragma unroll
            for (int r = 0; r < 4; ++r) {
                float rr = __shfl(rs, g * 4 + r);  // rare path
                #pragma unroll
                for (int vc = 0; vc < 8; ++vc) O[vc][r] *= rr;
            }
        }
        float ps = 0.f;
        #pragma unroll
        for (int i = 0; i < 8; ++i) {
            float p = __expf(sp[i] - m_run);       // bounded by e^8
            sp[i] = p;
            ps += p;
        }
        ps += __shfl_xor(ps, 16);
        ps += __shfl_xor(ps, 32);
        l_run += ps;

        // ---- fp32 tail: out[q][128|129]
        #pragma unroll
        for (int r = 0; r < 4; ++r) {
            int key0 = 8 * g + r;
            int key1 = 8 * (g ^ 2) + 4 + r;
            acct0 += sp[r] * Vt_s[0][key0] + sp[4 + r] * Vt_s[0][key1];
            acct1 += sp[r] * Vt_s[1][key0] + sp[4 + r] * Vt_s[1][key1];
        }

        // ---- P -> PV A-frag: own kh0 words + xor-32 swapped kh1 words
        unsigned w0h = packhi(sp[0], sp[1]), w1h = packhi(sp[2], sp[3]);
        unsigned w2h = packhi(sp[4], sp[5]), w3h = packhi(sp[6], sp[7]);
        unsigned w0l = packhi(sp[0] - truncbf(sp[0]), sp[1] - truncbf(sp[1]));
        unsigned w1l = packhi(sp[2] - truncbf(sp[2]), sp[3] - truncbf(sp[3]));
        unsigned w2l = packhi(sp[4] - truncbf(sp[4]), sp[5] - truncbf(sp[5]));
        unsigned w3l = packhi(sp[6] - truncbf(sp[6]), sp[7] - truncbf(sp[7]));
        FW4 PH, PL;
        PH.u[0] = w0h; PH.u[1] = w1h;
        PH.u[2] = __shfl_xor(w2h, 32);
        PH.u[3] = __shfl_xor(w3h, 32);
        PL.u[0] = w0l; PL.u[1] = w1l;
        PL.u[2] = __shfl_xor(w2l, 32);
        PL.u[3] = __shfl_xor(w3l, 32);
        bf16x8 PAH = PH.v, PAL = PL.v;

        // ---- F: O += P . V (3-term, 8 independent chains)
        #pragma unroll
        for (int vc = 0; vc < 8; ++vc) {
            bf16x8 vh = *(const bf16x8*)&Vf[0][vc][lane][0];
            bf16x8 vl = *(const bf16x8*)&Vf[1][vc][lane][0];
            O[vc] = __builtin_amdgcn_mfma_f32_16x16x32_bf16(PAH, vh, O[vc], 0, 0, 0);
            O[vc] = __builtin_amdgcn_mfma_f32_16x16x32_bf16(PAL, vh, O[vc], 0, 0, 0);
            O[vc] = __builtin_amdgcn_mfma_f32_16x16x32_bf16(PAH, vl, O[vc], 0, 0, 0);
        }

        __syncthreads();           // bar2: drains C loads; frees Vf/Kf[cur]
    }

    // ---- write partials (PV C layout: q = g*4+r, v = vc*16+q15)
    float* P = part + (size_t)((b * HH + h) * CT + c) * PSTRIDE;
    if (lane < 16) {
        P[qhalf * 16 + lane] = m_run;
        P[JJ + qhalf * 16 + lane] = l_run;
    }
    float* A = P + 2 * JJ;
    #pragma unroll
    for (int vc = 0; vc < 8; ++vc) {
        #pragma unroll
        for (int r = 0; r < 4; ++r) {
            int q = qhalf * 16 + g * 4 + r;
            A[q * VD + vc * 16 + q15] = O[vc][r];
        }
    }
    acct0 += __shfl_xor(acct0, 16);
    acct0 += __shfl_xor(acct0, 32);
    acct1 += __shfl_xor(acct1, 16);
    acct1 += __shfl_xor(acct1, 32);
    if (lane < 16) {
        A[(qhalf * 16 + lane) * VD + 128] = acct0;
        A[(qhalf * 16 + lane) * VD + 129] = acct1;
    }
}

// -------------------------------------------- fused combine + output MLP ----
__global__ __launch_bounds__(64) void comb_mlp_kernel(
        const float* __restrict__ part,
        const float* __restrict__ W3, const float* __restrict__ b3,
        const float* __restrict__ W4, const float* __restrict__ b4,
        const float* __restrict__ W5, const float* __restrict__ b5,
        float* __restrict__ out) {
    int row = blockIdx.x;          // b*J + j
    int b = row >> 5;
    int j = row & 31;
    int t = threadIdx.x;
    __shared__ float w_s[HH][CT];
    __shared__ float x[HH * VD];
    __shared__ float h1[64];
    __shared__ float h2[32];

    if (t < HH * CT) {
        int h = t / CT, cc = t % CT;
        const float* P = part + (size_t)((b * HH + h) * CT + cc) * PSTRIDE;
        float m = P[j];
        float l = P[JJ + j];
        float mm = m;
        #pragma unroll
        for (int s = 1; s < CT; s <<= 1) mm = fmaxf(mm, __shfl_xor(mm, s));
        float e = __expf(m - mm);
        float L = l * e;
        #pragma unroll
        for (int s = 1; s < CT; s <<= 1) L += __shfl_xor(L, s);
        w_s[h][cc] = (L > 0.f) ? e / L : 0.f;
    }
    __syncthreads();

    for (int idx = t; idx < HH * VD; idx += 64) {
        int h = idx / VD, v = idx - h * VD;
        const float* A = part + (size_t)(b * HH + h) * CT * PSTRIDE + 2 * JJ + j * VD + v;
        float o = 0.f;
        #pragma unroll 4
        for (int cc = 0; cc < CT; ++cc) o += w_s[h][cc] * A[(size_t)cc * PSTRIDE];
        x[idx] = o;
    }
    __syncthreads();

    float a0 = 0.f, a1 = 0.f, a2 = 0.f, a3 = 0.f;
    for (int i = 0; i < HH * VD; i += 4) {
        a0 += x[i] * W3[i * 64 + t];
        a1 += x[i + 1] * W3[(i + 1) * 64 + t];
        a2 += x[i + 2] * W3[(i + 2) * 64 + t];
        a3 += x[i + 3] * W3[(i + 3) * 64 + t];
    }
    h1[t] = fmaxf(b3[t] + (a0 + a1) + (a2 + a3), 0.f);
    __syncthreads();
    if (t < 32) {
        float c0 = 0.f, c1 = 0.f;
        for (int i = 0; i < 64; i += 2) {
            c0 += h1[i] * W4[i * 32 + t];
            c1 += h1[i + 1] * W4[(i + 1) * 32 + t];
        }
        h2[t] = fmaxf(b4[t] + c0 + c1, 0.f);
    }
    __syncthreads();
    if (t == 0) {
        float a3f = b5[0];
        for (int i = 0; i < 32; ++i) a3f += h2[i] * W5[i];
        out[row] = a3f;
    }
}

extern "C" void kernel_launch(void* const* d_in, const int* in_sizes, int n_in,
                              void* d_out, int out_size, void* d_ws, size_t ws_size,
                              hipStream_t stream) {
    const float* jq = (const float*)d_in[0];
    const float* Kg = (const float*)d_in[1];
    const float* Vg = (const float*)d_in[2];
    const int* mask = (const int*)d_in[3];
    const float* W1 = (const float*)d_in[4];
    const float* b1 = (const float*)d_in[5];
    const float* W2 = (const float*)d_in[6];
    const float* b2 = (const float*)d_in[7];
    const float* W3 = (const float*)d_in[8];
    const float* b3 = (const float*)d_in[9];
    const float* W4 = (const float*)d_in[10];
    const float* b4 = (const float*)d_in[11];
    const float* W5 = (const float*)d_in[12];
    const float* b5 = (const float*)d_in[13];
    float* out = (float*)d_out;

    float* ws = (float*)d_ws;
    float* qenc = ws;                                   // B*J*512 floats
    float* part = qenc + (size_t)BB * JJ * HH * KD;     // B*H*CT*PSTRIDE floats

    enc_kernel<<<BB * JJ, 64, 0, stream>>>(jq, W1, b1, W2, b2, qenc);
    attn_kernel<<<BB * CT * 2, 256, 0, stream>>>(Kg, Vg, mask, qenc, part);
    comb_mlp_kernel<<<BB * JJ, 64, 0, stream>>>(part, W3, b3, W4, b4, W5, b5, out);
}

// Round 13
// 109.708 us; speedup vs baseline: 2.2273x; 2.2273x over previous
//
#include <hip/hip_runtime.h>
#include <hip/hip_bf16.h>

#define BB 64
#define JJ 32
#define NN 4096
#define QD 130
#define KD 128
#define VD 130
#define HH 4
#define CT 4
#define NCH (NN / CT)                 // 1024
#define TIL (NCH / 32)                // 32
#define PSTRIDE (JJ + JJ + JJ * VD)   // 4224 floats per partial block

typedef __attribute__((ext_vector_type(8))) __bf16 bf16x8;
typedef __attribute__((ext_vector_type(4))) float  f32x4;

union FW4 { unsigned int u[4]; bf16x8 v; };

#define SEL_HI 0x07060302u

__device__ __forceinline__ unsigned int packhi(float f0, float f1) {
    return __builtin_amdgcn_perm(__float_as_uint(f1), __float_as_uint(f0), SEL_HI);
}
__device__ __forceinline__ float truncbf(float f) {
    return __uint_as_float(__float_as_uint(f) & 0xFFFF0000u);
}
// truncation split: 8 floats -> hi/lo bf16x8 planes (f = h + l + O(2^-17))
__device__ __forceinline__ void split8(float4 a, float4 b, bf16x8* h, bf16x8* l) {
    FW4 H, L;
    H.u[0] = packhi(a.x, a.y);
    H.u[1] = packhi(a.z, a.w);
    H.u[2] = packhi(b.x, b.y);
    H.u[3] = packhi(b.z, b.w);
    L.u[0] = packhi(a.x - truncbf(a.x), a.y - truncbf(a.y));
    L.u[1] = packhi(a.z - truncbf(a.z), a.w - truncbf(a.w));
    L.u[2] = packhi(b.x - truncbf(b.x), b.y - truncbf(b.y));
    L.u[3] = packhi(b.z - truncbf(b.z), b.w - truncbf(b.w));
    *h = H.v; *l = L.v;
}

// ---------------------------------------------------------------- encoder ---
__global__ __launch_bounds__(64) void enc_kernel(
        const float* __restrict__ jq,
        const float* __restrict__ W1, const float* __restrict__ b1,
        const float* __restrict__ W2, const float* __restrict__ b2,
        float* __restrict__ qenc) {
    int row = blockIdx.x;          // b*J + j
    int t = threadIdx.x;           // 0..63
    __shared__ float x[QD];
    __shared__ float h[64];
    for (int i = t; i < QD; i += 64) x[i] = jq[row * QD + i];
    __syncthreads();
    float a0 = 0.f, a1 = 0.f;
    for (int i = 0; i < QD - 1; i += 2) {
        a0 += x[i] * W1[i * 64 + t];
        a1 += x[i + 1] * W1[(i + 1) * 64 + t];
    }
    h[t] = fmaxf(b1[t] + a0 + a1, 0.f);
    __syncthreads();
    float a[8];
    #pragma unroll
    for (int s = 0; s < 8; ++s) a[s] = b2[t + 64 * s];
    for (int i = 0; i < 64; ++i) {
        float hv = h[i];
        #pragma unroll
        for (int s = 0; s < 8; ++s) a[s] += hv * W2[i * 512 + t + 64 * s];
    }
    #pragma unroll
    for (int s = 0; s < 8; ++s) qenc[row * 512 + t + 64 * s] = a[s];
}

// -------------------------------------------------------------- attention ---
// Block = (b, chunk of 1024 keys), 512 threads = 8 waves = 4 heads x 2
// q-halves, 1 block/CU (8-wave granularity pins occupancy; accepted).
// SKEWED T15 PIPELINE — softmax off the MFMA critical path:
//   phase1: QK(t) MFMAs || PV(t-1) MFMAs (independent) ; swriteK(t+1) ; bar1
//   phase2: softmax(t) -> P(t) regs ; swriteV(t+1) ; sload(t+2) ; bar2
// K and V both double-buffered. 17-skew LDS slots (slot=(i&15)+17*(i>>4))
// make both staging writes and fragment reads bank-conflict-free (the [65]
// row-pad left a 4-way write conflict: col stride 256B = 0-bank shift).
// (512,2): never force 4 waves/EU (rounds 4/9: cap < working set = spills).
__global__ __launch_bounds__(512, 2) void attn_kernel(
        const float* __restrict__ Kg, const float* __restrict__ Vg,
        const int* __restrict__ maskg, const float* __restrict__ qenc,
        float* __restrict__ part) {
    int blk = blockIdx.x;
    int c = blk & (CT - 1);
    int b = blk >> 2;              // CT==4
    int tid = threadIdx.x;
    int wid = tid >> 6;
    int lane = tid & 63;
    int h = wid & 3;               // head
    int qhalf = wid >> 2;          // 0: q 0..15, 1: q 16..31
    int g = lane >> 4;             // lane group 0..3
    int q15 = lane & 15;
    int idx17 = q15 + 17 * g;      // skewed fragment slot for this lane

    __shared__ __align__(16) __bf16 Kf[2][2][2][4][68][8];   // 34,816 B (dbuf)
    __shared__ __align__(16) __bf16 Vf[2][2][8][68][8];      // 34,816 B (dbuf)
    __shared__ float Vt_s[2][2][32];                         // V cols 128,129
    __shared__ int   msks[2][32];

    // stage geometry (key permutation for shfl_xor(32) P-exchange + 17-skew)
    int skey = tid >> 4;           // physical key 0..31
    int sdhi = tid & 15;           // d-chunk: d0 = sdhi*8
    int sa = skey >> 3, sb = skey & 7;
    int skh = sb >> 2;                               // target mfma instance
    int sm  = skh ? 4 * (sa ^ 2) + (sb & 3)          // target mfma row
                  : 4 * sa + sb;
    int slK = sm + 17 * (sdhi & 3);
    int skst = sdhi >> 2;
    int sv = tid & 127, skb = tid >> 7;              // skb 0..3
    int svc = sv >> 4, slV = (sv & 15) + 17 * skb;

    const float* Kb = Kg + (size_t)b * NN * KD;
    const float* Vb = Vg + (size_t)b * NN * VD;
    const int*   Mb = maskg + b * NN;

    float4 kfa, kfb;
    float  vf[8];
    float2 vt = {0.f, 0.f};
    int    mk = 0;

    auto sloadK = [&](int T) {
        int n0 = c * NCH + T * 32;
        const float* ks = Kb + (size_t)(n0 + skey) * KD + sdhi * 8;
        kfa = *(const float4*)ks;
        kfb = *(const float4*)(ks + 4);
    };
    auto sloadV = [&](int T) {
        int n0 = c * NCH + T * 32;
        const float* vs = Vb + (size_t)(n0 + skb * 8) * VD + sv;
        #pragma unroll
        for (int j = 0; j < 8; ++j) vf[j] = vs[(size_t)j * VD];
        if (tid < 32) {
            vt = *(const float2*)(Vb + (size_t)(n0 + tid) * VD + 128);
            mk = Mb[n0 + tid];
        }
    };
    auto swriteK = [&](int buf) {
        bf16x8 hh, ll;
        split8(kfa, kfb, &hh, &ll);
        *(bf16x8*)&Kf[buf][0][skh][skst][slK][0] = hh;
        *(bf16x8*)&Kf[buf][1][skh][skst][slK][0] = ll;
    };
    auto swriteV = [&](int buf) {
        bf16x8 hh, ll;
        float4 va = {vf[0], vf[1], vf[2], vf[3]};
        float4 vb2 = {vf[4], vf[5], vf[6], vf[7]};
        split8(va, vb2, &hh, &ll);
        *(bf16x8*)&Vf[buf][0][svc][slV][0] = hh;
        *(bf16x8*)&Vf[buf][1][svc][slV][0] = ll;
        if (tid < 32) {
            Vt_s[buf][0][tid] = vt.x;
            Vt_s[buf][1][tid] = vt.y;
            msks[buf][tid] = mk;
        }
    };

    sloadK(0);
    sloadV(0);

    // ---- Q B-frags (hi/lo): lane holds Q[d=kst*32+g*8+j][q=qhalf*16+q15]
    bf16x8 qh[4], ql[4];
    {
        const float* qrow = qenc + (size_t)(b * JJ + qhalf * 16 + q15) * 512
                            + h * KD + g * 8;
        #pragma unroll
        for (int kst = 0; kst < 4; ++kst) {
            float4 qa = *(const float4*)(qrow + kst * 32);
            float4 qb = *(const float4*)(qrow + kst * 32 + 4);
            split8(qa, qb, &qh[kst], &ql[kst]);
        }
    }

    swriteK(0);
    swriteV(0);
    sloadK(1);
    sloadV(1);
    __builtin_amdgcn_sched_barrier(0);

    f32x4 O[8];
    #pragma unroll
    for (int vc = 0; vc < 8; ++vc)
        #pragma unroll
        for (int r = 0; r < 4; ++r) O[vc][r] = 0.f;
    float acct0 = 0.f, acct1 = 0.f;
    float m_run = -1e30f, l_run = 0.f;
    bf16x8 PAH = {}, PAL = {};

    __syncthreads();               // tile 0 K,V visible

    for (int t = 0; t < TIL; ++t) {
        int cur = t & 1;

        // ======== phase 1: QK(t) || PV(t-1), then publish K(t+1) ========
        f32x4 S[2];
        #pragma unroll
        for (int kh = 0; kh < 2; ++kh)
            #pragma unroll
            for (int r = 0; r < 4; ++r) S[kh][r] = 0.f;
        #pragma unroll
        for (int kst = 0; kst < 4; ++kst) {
            #pragma unroll
            for (int kh = 0; kh < 2; ++kh) {
                bf16x8 khf = *(const bf16x8*)&Kf[cur][0][kh][kst][idx17][0];
                bf16x8 klf = *(const bf16x8*)&Kf[cur][1][kh][kst][idx17][0];
                S[kh] = __builtin_amdgcn_mfma_f32_16x16x32_bf16(khf, qh[kst], S[kh], 0, 0, 0);
                S[kh] = __builtin_amdgcn_mfma_f32_16x16x32_bf16(khf, ql[kst], S[kh], 0, 0, 0);
                S[kh] = __builtin_amdgcn_mfma_f32_16x16x32_bf16(klf, qh[kst], S[kh], 0, 0, 0);
            }
        }
        if (t > 0) {                     // PV(t-1): P(t-1) regs x V(t-1)
            #pragma unroll
            for (int vc = 0; vc < 8; ++vc) {
                bf16x8 vh = *(const bf16x8*)&Vf[cur ^ 1][0][vc][idx17][0];
                bf16x8 vl = *(const bf16x8*)&Vf[cur ^ 1][1][vc][idx17][0];
                O[vc] = __builtin_amdgcn_mfma_f32_16x16x32_bf16(PAH, vh, O[vc], 0, 0, 0);
                O[vc] = __builtin_amdgcn_mfma_f32_16x16x32_bf16(PAL, vh, O[vc], 0, 0, 0);
                O[vc] = __builtin_amdgcn_mfma_f32_16x16x32_bf16(PAH, vl, O[vc], 0, 0, 0);
            }
        }
        __builtin_amdgcn_sched_barrier(0);
        if (t + 1 < TIL) swriteK((t + 1) & 1);   // vmcnt wait lands ~1 phase late
        __syncthreads();           // bar1

        // ======== phase 2: softmax(t), publish V(t+1), prefetch t+2 ========
        unsigned int mword = (unsigned int)__ballot(msks[cur][lane & 31] != 0);
        const float sc = 0.08838834764831845f;
        float sp[8];
        float rm = -1e30f;
        #pragma unroll
        for (int r = 0; r < 4; ++r) {
            int key0 = 8 * g + r;
            float s0 = ((mword >> key0) & 1u) ? -1e30f : S[0][r] * sc;
            sp[r] = s0;
            rm = fmaxf(rm, s0);
            int key1 = 8 * (g ^ 2) + 4 + r;
            float s1 = ((mword >> key1) & 1u) ? -1e30f : S[1][r] * sc;
            sp[4 + r] = s1;
            rm = fmaxf(rm, s1);
        }
        rm = fmaxf(rm, __shfl_xor(rm, 16));
        rm = fmaxf(rm, __shfl_xor(rm, 32));
        if (!__all(rm <= m_run + 8.f)) {          // T13 defer-max
            float mn = fmaxf(m_run, rm);
            float rs = __expf(m_run - mn);
            m_run = mn;
            l_run *= rs; acct0 *= rs; acct1 *= rs;
            #pragma unroll
            for (int r = 0; r < 4; ++r) {
                float rr = __shfl(rs, g * 4 + r);  // rare path
                #pragma unroll
                for (int vc = 0; vc < 8; ++vc) O[vc][r] *= rr;
            }
        }
        float ps = 0.f;
        #pragma unroll
        for (int i = 0; i < 8; ++i) {
            float p = __expf(sp[i] - m_run);       // bounded by e^8
            sp[i] = p;
            ps += p;
        }
        ps += __shfl_xor(ps, 16);
        ps += __shfl_xor(ps, 32);
        l_run += ps;

        // fp32 tail: out[q][128|129]
        #pragma unroll
        for (int r = 0; r < 4; ++r) {
            int key0 = 8 * g + r;
            int key1 = 8 * (g ^ 2) + 4 + r;
            acct0 += sp[r] * Vt_s[cur][0][key0] + sp[4 + r] * Vt_s[cur][0][key1];
            acct1 += sp[r] * Vt_s[cur][1][key0] + sp[4 + r] * Vt_s[cur][1][key1];
        }

        // P(t) -> PV A-frag: own kh0 words + xor-32 swapped kh1 words
        unsigned w0h = packhi(sp[0], sp[1]), w1h = packhi(sp[2], sp[3]);
        unsigned w2h = packhi(sp[4], sp[5]), w3h = packhi(sp[6], sp[7]);
        unsigned w0l = packhi(sp[0] - truncbf(sp[0]), sp[1] - truncbf(sp[1]));
        unsigned w1l = packhi(sp[2] - truncbf(sp[2]), sp[3] - truncbf(sp[3]));
        unsigned w2l = packhi(sp[4] - truncbf(sp[4]), sp[5] - truncbf(sp[5]));
        unsigned w3l = packhi(sp[6] - truncbf(sp[6]), sp[7] - truncbf(sp[7]));
        FW4 PH, PL;
        PH.u[0] = w0h; PH.u[1] = w1h;
        PH.u[2] = __shfl_xor(w2h, 32);
        PH.u[3] = __shfl_xor(w3h, 32);
        PL.u[0] = w0l; PL.u[1] = w1l;
        PL.u[2] = __shfl_xor(w2l, 32);
        PL.u[3] = __shfl_xor(w3l, 32);
        PAH = PH.v; PAL = PL.v;

        __builtin_amdgcn_sched_barrier(0);
        if (t + 1 < TIL) swriteV((t + 1) & 1);
        if (t + 2 < TIL) { sloadK(t + 2); sloadV(t + 2); }
        __syncthreads();           // bar2
    }

    // ---- epilogue: PV(TIL-1)
    {
        int lastb = (TIL - 1) & 1;
        #pragma unroll
        for (int vc = 0; vc < 8; ++vc) {
            bf16x8 vh = *(const bf16x8*)&Vf[lastb][0][vc][idx17][0];
            bf16x8 vl = *(const bf16x8*)&Vf[lastb][1][vc][idx17][0];
            O[vc] = __builtin_amdgcn_mfma_f32_16x16x32_bf16(PAH, vh, O[vc], 0, 0, 0);
            O[vc] = __builtin_amdgcn_mfma_f32_16x16x32_bf16(PAL, vh, O[vc], 0, 0, 0);
            O[vc] = __builtin_amdgcn_mfma_f32_16x16x32_bf16(PAH, vl, O[vc], 0, 0, 0);
        }
    }

    // ---- write partials (PV C layout: q = g*4+r, v = vc*16+q15)
    float* P = part + (size_t)((b * HH + h) * CT + c) * PSTRIDE;
    if (lane < 16) {
        P[qhalf * 16 + lane] = m_run;
        P[JJ + qhalf * 16 + lane] = l_run;
    }
    float* A = P + 2 * JJ;
    #pragma unroll
    for (int vc = 0; vc < 8; ++vc) {
        #pragma unroll
        for (int r = 0; r < 4; ++r) {
            int q = qhalf * 16 + g * 4 + r;
            A[q * VD + vc * 16 + q15] = O[vc][r];
        }
    }
    acct0 += __shfl_xor(acct0, 16);
    acct0 += __shfl_xor(acct0, 32);
    acct1 += __shfl_xor(acct1, 16);
    acct1 += __shfl_xor(acct1, 32);
    if (lane < 16) {
        A[(qhalf * 16 + lane) * VD + 128] = acct0;
        A[(qhalf * 16 + lane) * VD + 129] = acct1;
    }
}

// -------------------------------------------- fused combine + output MLP ----
__global__ __launch_bounds__(64) void comb_mlp_kernel(
        const float* __restrict__ part,
        const float* __restrict__ W3, const float* __restrict__ b3,
        const float* __restrict__ W4, const float* __restrict__ b4,
        const float* __restrict__ W5, const float* __restrict__ b5,
        float* __restrict__ out) {
    int row = blockIdx.x;          // b*J + j
    int b = row >> 5;
    int j = row & 31;
    int t = threadIdx.x;
    __shared__ float w_s[HH][CT];
    __shared__ float x[HH * VD];
    __shared__ float h1[64];
    __shared__ float h2[32];

    if (t < HH * CT) {             // 16 threads
        int h = t / CT, cc = t % CT;
        const float* P = part + (size_t)((b * HH + h) * CT + cc) * PSTRIDE;
        float m = P[j];
        float l = P[JJ + j];
        float mm = m;
        #pragma unroll
        for (int s = 1; s < CT; s <<= 1) mm = fmaxf(mm, __shfl_xor(mm, s));
        float e = __expf(m - mm);
        float L = l * e;
        #pragma unroll
        for (int s = 1; s < CT; s <<= 1) L += __shfl_xor(L, s);
        w_s[h][cc] = (L > 0.f) ? e / L : 0.f;
    }
    __syncthreads();

    for (int idx = t; idx < HH * VD; idx += 64) {
        int h = idx / VD, v = idx - h * VD;
        const float* A = part + (size_t)(b * HH + h) * CT * PSTRIDE + 2 * JJ + j * VD + v;
        float o = 0.f;
        #pragma unroll
        for (int cc = 0; cc < CT; ++cc) o += w_s[h][cc] * A[(size_t)cc * PSTRIDE];
        x[idx] = o;
    }
    __syncthreads();

    float a0 = 0.f, a1 = 0.f, a2 = 0.f, a3 = 0.f;
    for (int i = 0; i < HH * VD; i += 4) {
        a0 += x[i] * W3[i * 64 + t];
        a1 += x[i + 1] * W3[(i + 1) * 64 + t];
        a2 += x[i + 2] * W3[(i + 2) * 64 + t];
        a3 += x[i + 3] * W3[(i + 3) * 64 + t];
    }
    h1[t] = fmaxf(b3[t] + (a0 + a1) + (a2 + a3), 0.f);
    __syncthreads();
    if (t < 32) {
        float c0 = 0.f, c1 = 0.f;
        for (int i = 0; i < 64; i += 2) {
            c0 += h1[i] * W4[i * 32 + t];
            c1 += h1[i + 1] * W4[(i + 1) * 32 + t];
        }
        h2[t] = fmaxf(b4[t] + c0 + c1, 0.f);
    }
    __syncthreads();
    if (t == 0) {
        float a3f = b5[0];
        for (int i = 0; i < 32; ++i) a3f += h2[i] * W5[i];
        out[row] = a3f;
    }
}

extern "C" void kernel_launch(void* const* d_in, const int* in_sizes, int n_in,
                              void* d_out, int out_size, void* d_ws, size_t ws_size,
                              hipStream_t stream) {
    const float* jq = (const float*)d_in[0];
    const float* Kg = (const float*)d_in[1];
    const float* Vg = (const float*)d_in[2];
    const int* mask = (const int*)d_in[3];
    const float* W1 = (const float*)d_in[4];
    const float* b1 = (const float*)d_in[5];
    const float* W2 = (const float*)d_in[6];
    const float* b2 = (const float*)d_in[7];
    const float* W3 = (const float*)d_in[8];
    const float* b3 = (const float*)d_in[9];
    const float* W4 = (const float*)d_in[10];
    const float* b4 = (const float*)d_in[11];
    const float* W5 = (const float*)d_in[12];
    const float* b5 = (const float*)d_in[13];
    float* out = (float*)d_out;

    float* ws = (float*)d_ws;
    float* qenc = ws;                                   // B*J*512 floats
    float* part = qenc + (size_t)BB * JJ * HH * KD;     // B*H*CT*PSTRIDE floats

    enc_kernel<<<BB * JJ, 64, 0, stream>>>(jq, W1, b1, W2, b2, qenc);
    attn_kernel<<<BB * CT, 512, 0, stream>>>(Kg, Vg, mask, qenc, part);
    comb_mlp_kernel<<<BB * JJ, 64, 0, stream>>>(part, W3, b3, W4, b4, W5, b5, out);
}